// Round 12
// baseline (241.675 us; speedup 1.0000x reference)
//
#include <hip/hip_runtime.h>
#include <math.h>
#include <float.h>

#define NB 4096
#define ND 256
#define NK 25
#define EPSF 1e-8f
#define CAP 256          // per-row candidate capacity (fast path)
#define CAP_FB 1024      // fixup candidate capacity
#define CTGT 192         // fixup bisection target
#define LCAP 16          // per-lane candidate slots (exactly fills the 32KB union)

typedef __attribute__((ext_vector_type(8))) short bf16x8;
typedef __attribute__((ext_vector_type(4))) float f32x4;

#define GLD_LDS16(gp, lp)                                                   \
    __builtin_amdgcn_global_load_lds(                                       \
        (const __attribute__((address_space(1))) void*)(uintptr_t)(gp),     \
        (__attribute__((address_space(3))) void*)(uint32_t)(uintptr_t)(lp), \
        16, 0, 0)

__device__ inline short f2bf(float x) {
    unsigned u = __float_as_uint(x);
    return (short)((u + 0x7FFF + ((u >> 16) & 1)) >> 16);
}
__device__ inline float bf2f(short s) {
    return __uint_as_float(((unsigned)(unsigned short)s) << 16);
}

// ---------------------------------------------------------------- prep: bf16 cast + ||f||^2
__global__ __launch_bounds__(64) void prep_kernel(const float* __restrict__ f,
                                                  short* __restrict__ fh,
                                                  float* __restrict__ sq) {
    int row  = blockIdx.x;
    int lane = threadIdx.x;
    float4 v = ((const float4*)(f + (size_t)row * ND))[lane];
    float acc = v.x * v.x + v.y * v.y + v.z * v.z + v.w * v.w;
    *(short4*)(fh + (size_t)row * ND + lane * 4) =
        make_short4(f2bf(v.x), f2bf(v.y), f2bf(v.z), f2bf(v.w));
#pragma unroll
    for (int off = 32; off; off >>= 1) acc += __shfl_down(acc, off);
    if (lane == 0) sq[row] = acc;
}

// ---------------------------------------------------------------- mstat: per-row threshold; zero cnt/flag
__global__ __launch_bounds__(256) void mstat_kernel(const float* __restrict__ sq,
                                                    float* __restrict__ T,
                                                    int* __restrict__ cnt,
                                                    int* __restrict__ flag) {
    int tid = threadIdx.x;
    __shared__ float r1[4], r2[4];
    float a1 = 0.f, a2 = 0.f;
    for (int t = tid; t < NB; t += 256) { float s = sq[t]; a1 += s; a2 += s * s; }
#pragma unroll
    for (int off = 32; off; off >>= 1) { a1 += __shfl_xor(a1, off); a2 += __shfl_xor(a2, off); }
    if ((tid & 63) == 0) { r1[tid >> 6] = a1; r2[tid >> 6] = a2; }
    __syncthreads();
    float M1 = (r1[0] + r1[1] + r1[2] + r1[3]) * (1.0f / NB);
    float M2 = (r2[0] + r2[1] + r2[2] + r2[3]) * (1.0f / NB);
    float varsq = fmaxf(M2 - M1 * M1, 0.f);
    for (int t = tid; t < NB; t += 256) {
        float s = sq[t];
        float sig = sqrtf(varsq + 4.f * s);
        T[t] = s + M1 - 2.0f * sig;              // mu_i - 2*sigma_i
        cnt[t]  = 0;
        flag[t] = 0;
    }
}

// ---------------------------------------------------------------- MFMA Gram + compressed candidate append
#define BM 128
#define BK 64
__global__ __launch_bounds__(256) void gram_kernel(const short* __restrict__ fh,
                                                   const float* __restrict__ sq,
                                                   const float* __restrict__ T,
                                                   int* __restrict__ cnt,
                                                   int* __restrict__ flag,
                                                   float2* __restrict__ cand) {
    // As/Bs are dead after the K-loop; candidate slots overlay them (both 32 KB).
    __shared__ __align__(16) union SMem {
        short ab[2 * BM * BK];                                  // 32 KB staging
        struct { float d[256 * LCAP]; int k[256 * LCAP]; } cb;  // 32 KB slots
    } smem;
    __shared__ float sT[BM];
    short* As = smem.ab;
    short* Bs = smem.ab + BM * BK;

    int b   = blockIdx.x;
    int ti  = (b >> 5) * BM;
    int tj  = (b & 31) * BM;
    int tid = threadIdx.x;
    int w = tid >> 6, lane = tid & 63;
    int wr = w >> 1, wc = w & 1;
    int fr = lane & 15, fq = lane >> 4;

    if (tid < BM) sT[tid] = T[ti + tid];         // visible after first loop barrier

    f32x4 acc[4][4];
#pragma unroll
    for (int m = 0; m < 4; ++m)
#pragma unroll
        for (int n = 0; n < 4; ++n) acc[m][n] = (f32x4){0.f, 0.f, 0.f, 0.f};

    int srow = lane >> 3;
    int scol = (lane & 7) * 8;

    for (int s = 0; s < 4; ++s) {
        int k0 = s * 64;
#pragma unroll
        for (int i = 0; i < 4; ++i) {
            int c   = 4 * w + i;
            int row = c * 8 + srow;
            GLD_LDS16(fh + (size_t)(ti + row) * ND + k0 + scol, As + c * 512);
            GLD_LDS16(fh + (size_t)(tj + row) * ND + k0 + scol, Bs + c * 512);
        }
        __syncthreads();
#pragma unroll
        for (int kk = 0; kk < 2; ++kk) {
            bf16x8 af[4], bfr[4];
#pragma unroll
            for (int m = 0; m < 4; ++m)
                af[m] = *(const bf16x8*)(As + (wr * 64 + m * 16 + fr) * 64 + kk * 32 + fq * 8);
#pragma unroll
            for (int n = 0; n < 4; ++n)
                bfr[n] = *(const bf16x8*)(Bs + (wc * 64 + n * 16 + fr) * 64 + kk * 32 + fq * 8);
#pragma unroll
            for (int m = 0; m < 4; ++m)
#pragma unroll
                for (int n = 0; n < 4; ++n)
                    acc[m][n] = __builtin_amdgcn_mfma_f32_16x16x32_bf16(af[m], bfr[n], acc[m][n], 0, 0, 0);
        }
        __syncthreads();                          // last iter: LDS reads drained -> overlay safe
    }

    // phase 1: filter into per-lane LDS slots (no atomics, no dependent latency)
    float* cbd = smem.cb.d;
    int*   cbk = smem.cb.k;
    int nc = 0;
#pragma unroll
    for (int m = 0; m < 4; ++m) {
#pragma unroll
        for (int j = 0; j < 4; ++j) {
            int rl = wr * 64 + m * 16 + fq * 4 + j;
            int gi = ti + rl;
            float si = sq[gi];
            float Tr = sT[rl];
#pragma unroll
            for (int n = 0; n < 4; ++n) {
                int col = tj + wc * 64 + n * 16 + fr;
                float d = fmaxf(si + sq[col] - 2.f * acc[m][n][j], 0.f);
                if (d < Tr) {
                    if (nc < LCAP) {
                        cbd[tid * LCAP + nc] = d;
                        cbk[tid * LCAP + nc] = (rl << 12) | col;
                        ++nc;
                    } else {
                        flag[gi] = 1;             // lane overflow -> exact fixup
                    }
                }
            }
        }
    }

    // phase 2: short append loop (~6 dependent round-trips instead of ~49)
    int kmax = nc;
#pragma unroll
    for (int off = 32; off; off >>= 1) kmax = max(kmax, __shfl_xor(kmax, off));
    for (int k = 0; k < kmax; ++k) {
        if (k < nc) {
            float d  = cbd[tid * LCAP + k];
            int  key = cbk[tid * LCAP + k];
            int  gi2 = ti + (key >> 12);
            int  col = key & 4095;
            int pos = atomicAdd(&cnt[gi2], 1);
            if (pos < CAP) cand[(size_t)gi2 * CAP + pos] = make_float2(d, __int_as_float(col));
            else flag[gi2] = 1;
        }
    }
}

// ---------------------------------------------------------------- topk5: exact rank-select among candidates
__global__ __launch_bounds__(256) void topk5_kernel(const float2* __restrict__ cand,
                                                    const int* __restrict__ cnt,
                                                    int* __restrict__ flag,
                                                    int* __restrict__ idxk,
                                                    float* __restrict__ dk,
                                                    float* __restrict__ sigma) {
    int wid  = threadIdx.x >> 6;
    int lane = threadIdx.x & 63;
    int row  = blockIdx.x * 4 + wid;
    int c = cnt[row];
    if (c < NK || c > CAP) { if (lane == 0) flag[row] = 1; return; }
    if (flag[row]) return;                        // lane-overflow rows -> fixup
    int slots = (c + 63) >> 6;

    float v[4]; int id[4];
#pragma unroll
    for (int k = 0; k < 4; ++k) {
        int p = lane + 64 * k;
        if (p < c) {
            float2 q = cand[(size_t)row * CAP + p];
            v[k] = q.x; id[k] = __float_as_int(q.y);
        } else { v[k] = FLT_MAX; id[k] = 0x7fffffff; }
    }
    int rank[4] = {0, 0, 0, 0};
    for (int s = 0; s < 64; ++s) {
        int sl = (lane + s) & 63;
#pragma unroll
        for (int k2 = 0; k2 < 4; ++k2) {
            if (k2 < slots) {
                float y  = __shfl(v[k2], sl);
                int   yi = __shfl(id[k2], sl);
#pragma unroll
                for (int k = 0; k < 4; ++k) {
                    if (k < slots) {
                        bool lt = (y < v[k]) || (y == v[k] && yi < id[k]);
                        rank[k] += lt ? 1 : 0;
                    }
                }
            }
        }
    }
    float t = 0.f;
#pragma unroll
    for (int k = 0; k < 4; ++k) {
        if (k < slots && v[k] != FLT_MAX && rank[k] < NK) {
            idxk[row * NK + rank[k]] = id[k];
            dk[row * NK + rank[k]]   = v[k];
            t += sqrtf(v[k] + EPSF);
        }
    }
#pragma unroll
    for (int off = 32; off; off >>= 1) t += __shfl_xor(t, off);
    if (lane == 0) sigma[row] = t * (1.0f / NK);
}

// ---------------------------------------------------------------- fixup: exact recompute for flagged rows (vectorized)
__global__ __launch_bounds__(256) void fixup_kernel(const short* __restrict__ fh,
                                                    const float* __restrict__ sq,
                                                    const int* __restrict__ flag,
                                                    int* __restrict__ idxk,
                                                    float* __restrict__ dk,
                                                    float* __restrict__ sigma) {
    int row = blockIdx.x;
    if (flag[row] == 0) return;
    __shared__ float rowv[NB];
    __shared__ __align__(16) float frv[ND];
    __shared__ float cval[CAP_FB];
    __shared__ int   cidx[CAP_FB];
    __shared__ int   red[4];
    __shared__ float redf[4];
    __shared__ int   s_cnt;
    int tid = threadIdx.x;

    for (int a = tid; a < ND; a += 256) frv[a] = bf2f(fh[(size_t)row * ND + a]);
    __syncthreads();
    float sqr = sq[row];
    for (int c = tid; c < NB; c += 256) {
        const short4* fc4 = (const short4*)(fh + (size_t)c * ND);
        float acc = 0.f;
#pragma unroll 8
        for (int a4 = 0; a4 < ND / 4; ++a4) {
            short4 q  = fc4[a4];
            float4 fv = *(const float4*)&frv[a4 * 4];
            acc += fv.x * bf2f(q.x) + fv.y * bf2f(q.y)
                 + fv.z * bf2f(q.z) + fv.w * bf2f(q.w);
        }
        rowv[c] = fmaxf(sqr + sq[c] - 2.f * acc, 0.f);
    }
    __syncthreads();

    float mx = 0.f;
    for (int t = tid; t < NB; t += 256) mx = fmaxf(mx, rowv[t]);
#pragma unroll
    for (int off = 32; off; off >>= 1) mx = fmaxf(mx, __shfl_xor(mx, off));
    if ((tid & 63) == 0) redf[tid >> 6] = mx;
    __syncthreads();
    mx = fmaxf(fmaxf(redf[0], redf[1]), fmaxf(redf[2], redf[3]));

    unsigned lo = 0u, hi = __float_as_uint(mx) + 1u;
    int cnt_hi = NB;
    for (int it = 0; it < 34; ++it) {
        if (cnt_hi <= CTGT || hi <= lo + 1u) break;
        unsigned mid = (lo + hi) >> 1;
        float Tm = __uint_as_float(mid);
        int c = 0;
        for (int t = tid; t < NB; t += 256) c += (rowv[t] < Tm) ? 1 : 0;
#pragma unroll
        for (int off = 32; off; off >>= 1) c += __shfl_xor(c, off);
        __syncthreads();
        if ((tid & 63) == 0) red[tid >> 6] = c;
        __syncthreads();
        c = red[0] + red[1] + red[2] + red[3];
        if (c >= NK) { hi = mid; cnt_hi = c; } else { lo = mid; }
    }
    float Thi = __uint_as_float(hi);
    if (tid == 0) s_cnt = 0;
    __syncthreads();
    for (int t = tid; t < NB; t += 256) {
        if (rowv[t] < Thi) {
            int p = atomicAdd(&s_cnt, 1);
            if (p < CAP_FB) { cval[p] = rowv[t]; cidx[p] = t; }
        }
    }
    __syncthreads();
    int cnt = min(s_cnt, CAP_FB);

    if (tid < 64) {
        float ssum = 0.f;
        for (int it = 0; it < NK; ++it) {
            float bv = FLT_MAX; int bi = NB; int bp = -1;
            for (int r = tid; r < cnt; r += 64) {
                float cv = cval[r]; int ci = cidx[r];
                if (cv < bv || (cv == bv && ci < bi)) { bv = cv; bi = ci; bp = r; }
            }
#pragma unroll
            for (int off = 32; off; off >>= 1) {
                float ov = __shfl_down(bv, off);
                int   oi = __shfl_down(bi, off);
                int   op = __shfl_down(bp, off);
                if (ov < bv || (ov == bv && oi < bi)) { bv = ov; bi = oi; bp = op; }
            }
            bp = __shfl(bp, 0); bv = __shfl(bv, 0); bi = __shfl(bi, 0);
            if (tid == 0) {
                idxk[row * NK + it] = bi;
                dk[row * NK + it]   = bv;
                cval[bp] = FLT_MAX;
            }
            ssum += sqrtf(bv + EPSF);
        }
        if (tid == 0) sigma[row] = ssum * (1.0f / NK);
    }
}

// ---------------------------------------------------------------- P rows + score-sorted prefix tables
__global__ __launch_bounds__(64) void buildp_kernel(const int* __restrict__ idxk,
                                                    const float* __restrict__ dk,
                                                    const float* __restrict__ sigma,
                                                    const int* __restrict__ labels,
                                                    const float* __restrict__ scores,
                                                    float* __restrict__ pval,
                                                    float* __restrict__ bs,
                                                    float2* __restrict__ cs) {
    int row  = blockIdx.x;
    int lane = threadIdx.x;
    __shared__ float sb[32];
    __shared__ float sp[32];

    float w = 0.f;
    int j = 0;
    if (lane < NK) {
        j = idxk[row * NK + lane];
        bool mut = false;
        for (int n = 0; n < NK; ++n) mut |= (idxk[j * NK + n] == row);
        bool dir = labels[row] <= labels[j];
        float sij = sigma[row] * sigma[j] + EPSF;
        w = (mut && dir) ? expf(-dk[row * NK + lane] / sij) : 0.f;
        if (j == row) w += 1.f;
    }
    float rs = w;
#pragma unroll
    for (int off = 32; off; off >>= 1) rs += __shfl_down(rs, off);
    rs = __shfl(rs, 0);
    float pv = (lane < NK) ? w / (rs + EPSF) : 0.f;
    if (lane < NK) pval[row * NK + lane] = pv;

    float sj = (lane < NK) ? scores[j] : FLT_MAX;
    int rank = 0;
#pragma unroll
    for (int u = 0; u < NK; ++u) {
        float su = __shfl(sj, u);
        rank += (su < sj || (su == sj && u < lane)) ? 1 : 0;
    }
    if (lane < 32) { sb[lane] = FLT_MAX; sp[lane] = 0.f; }
    __syncthreads();
    if (lane < NK) { sb[rank] = sj; sp[rank] = pv; }
    __syncthreads();

    float b = sb[lane & 31];
    float p = sp[lane & 31];
    float c  = p;
    float s2 = p * b;
#pragma unroll
    for (int off = 1; off < 32; off <<= 1) {
        float oc = __shfl_up(c, off);
        float os = __shfl_up(s2, off);
        if (lane >= off) { c += oc; s2 += os; }
    }
    float ce = __shfl_up(c, 1);
    float se = __shfl_up(s2, 1);
    if (lane == 0) { ce = 0.f; se = 0.f; }
    if (lane < 32) {
        bs[row * 32 + lane] = b;
        cs[row * 32 + lane] = make_float2(ce, se);
    }
}

// ---------------------------------------------------------------- hval: per-j G/H at the 25 needed points
__global__ __launch_bounds__(256) void hval_kernel(const int* __restrict__ idxk,
                                                   const float* __restrict__ pval,
                                                   const float* __restrict__ scores,
                                                   const float* __restrict__ bs,
                                                   const float2* __restrict__ cs,
                                                   float* __restrict__ Gval,
                                                   float* __restrict__ Hval) {
    int wid  = threadIdx.x >> 6;
    int lane = threadIdx.x & 63;
    int j    = blockIdx.x * 4 + wid;
    __shared__ float2 slab[4][NK][26];

    int  ln = (lane < NK) ? lane : NK - 1;
    int  q  = idxk[j * NK + ln];
    float p = (lane < NK) ? pval[j * NK + lane] : 0.f;
    float sqv = scores[q];

    float4 bq[7];
    const float4* b4 = (const float4*)(bs + q * 32);
#pragma unroll
    for (int t = 0; t < 7; ++t) bq[t] = b4[t];
    const float4* c4 = (const float4*)(cs + q * 32);
    if (lane < NK) {
#pragma unroll
        for (int t = 0; t < 13; ++t)
            *(float4*)&slab[wid][lane][t * 2] = c4[t];
    }

    float bjj = bs[j * 32 + lane];
    int posj = 0;
#pragma unroll
    for (int r = 0; r < NK; ++r)
        posj += (__shfl(bjj, r) < sqv) ? 1 : 0;
    float2 cj = cs[j * 32 + posj];
    if (lane < NK) Gval[j * 32 + lane] = sqv * cj.x - cj.y;

    __syncthreads();

    for (int u = 0; u < NK; ++u) {
        float x = __shfl(sqv, u);
        int pos = 0;
#pragma unroll
        for (int t = 0; t < 7; ++t) {
            float4 b = bq[t];
            pos += (b.x < x) + (b.y < x) + (b.z < x) + (b.w < x);
        }
        float2 ch = slab[wid][ln][pos];
        float g = p * (x * ch.x - ch.y);
#pragma unroll
        for (int off = 32; off; off >>= 1) g += __shfl_xor(g, off);
        if (lane == 0) Hval[j * 32 + u] = g;
    }
}

// ---------------------------------------------------------------- final loss: per-wave partial
__global__ __launch_bounds__(256) void loss_kernel(const float* __restrict__ scores,
                                                   const int* __restrict__ idxk,
                                                   const float* __restrict__ pval,
                                                   const float* __restrict__ Gval,
                                                   const float* __restrict__ Hval,
                                                   float* __restrict__ partial) {
    int wid  = threadIdx.x >> 6;
    int lane = threadIdx.x & 63;
    int i    = blockIdx.x * 4 + wid;
    float si = scores[i];
    float acc = 0.f;
    if (lane < NK) {
        int   jm = idxk[i * NK + lane];
        float pm = pval[i * NK + lane];
        float sj = scores[jm];
        int slot = -1;
        const int* row = idxk + jm * NK;
#pragma unroll
        for (int n = 0; n < NK; ++n)
            if (row[n] == i) slot = n;
        float g = 0.f, h = 0.f;
        if (slot >= 0) {
            g = Gval[jm * 32 + slot];
            h = Hval[jm * 32 + slot];
        }
        acc = pm * (fmaxf(si - sj, 0.f) + 0.5f * g + (1.f / 3.f) * h);
    }
#pragma unroll
    for (int off = 32; off; off >>= 1) acc += __shfl_xor(acc, off);
    if (lane == 0) partial[i] = acc;
}

// ---------------------------------------------------------------- final reduce
__global__ __launch_bounds__(256) void reduce_kernel(const float* __restrict__ partial,
                                                     float* __restrict__ out) {
    int tid = threadIdx.x;
    __shared__ float red[4];
    float a = 0.f;
    for (int t = tid; t < NB / 4; t += 256) {
        float4 p = ((const float4*)partial)[t];
        a += p.x + p.y + p.z + p.w;
    }
#pragma unroll
    for (int off = 32; off; off >>= 1) a += __shfl_xor(a, off);
    if ((tid & 63) == 0) red[tid >> 6] = a;
    __syncthreads();
    if (tid == 0) out[0] = (red[0] + red[1] + red[2] + red[3]) * (1.0f / NB);
}

// ---------------------------------------------------------------- launch
extern "C" void kernel_launch(void* const* d_in, const int* in_sizes, int n_in,
                              void* d_out, int out_size, void* d_ws, size_t ws_size,
                              hipStream_t stream) {
    const float* features = (const float*)d_in[0];
    const float* scores   = (const float*)d_in[1];
    const int*   labels   = (const int*)d_in[2];
    float* out = (float*)d_out;

    char* ws = (char*)d_ws;
    size_t off = 0;
    float2* cand    = (float2*)(ws + off); off += (size_t)NB * CAP * 8;
    short*  fh      = (short*) (ws + off); off += (size_t)NB * ND * 2;
    float*  sq      = (float*) (ws + off); off += (size_t)NB * 4;
    float*  T       = (float*) (ws + off); off += (size_t)NB * 4;
    int*    cnt     = (int*)   (ws + off); off += (size_t)NB * 4;
    int*    flag    = (int*)   (ws + off); off += (size_t)NB * 4;
    int*    idxk    = (int*)   (ws + off); off += (size_t)NB * NK * 4;
    float*  dk      = (float*) (ws + off); off += (size_t)NB * NK * 4;
    float*  sigma   = (float*) (ws + off); off += (size_t)NB * 4;
    float*  pval    = (float*) (ws + off); off += (size_t)NB * NK * 4;
    float*  bs      = (float*) (ws + off); off += (size_t)NB * 32 * 4;
    float2* cs      = (float2*)(ws + off); off += (size_t)NB * 32 * 8;
    float*  Gval    = (float*) (ws + off); off += (size_t)NB * 32 * 4;
    float*  Hval    = (float*) (ws + off); off += (size_t)NB * 32 * 4;
    float*  partial = (float*) (ws + off); off += (size_t)NB * 4;

    prep_kernel<<<NB, 64, 0, stream>>>(features, fh, sq);
    mstat_kernel<<<1, 256, 0, stream>>>(sq, T, cnt, flag);
    gram_kernel<<<(NB / BM) * (NB / BM), 256, 0, stream>>>(fh, sq, T, cnt, flag, cand);
    topk5_kernel<<<NB / 4, 256, 0, stream>>>(cand, cnt, flag, idxk, dk, sigma);
    fixup_kernel<<<NB, 256, 0, stream>>>(fh, sq, flag, idxk, dk, sigma);
    buildp_kernel<<<NB, 64, 0, stream>>>(idxk, dk, sigma, labels, scores, pval, bs, cs);
    hval_kernel<<<NB / 4, 256, 0, stream>>>(idxk, pval, scores, bs, cs, Gval, Hval);
    loss_kernel<<<NB / 4, 256, 0, stream>>>(scores, idxk, pval, Gval, Hval, partial);
    reduce_kernel<<<1, 256, 0, stream>>>(partial, out);
}

// Round 13
// 184.982 us; speedup vs baseline: 1.3065x; 1.3065x over previous
//
#include <hip/hip_runtime.h>
#include <math.h>
#include <float.h>

#define NB 4096
#define ND 256
#define NK 25
#define EPSF 1e-8f
#define CAP 256          // per-row candidate capacity (fast path)
#define CAP_FB 1024      // fixup candidate capacity
#define CTGT 192         // fixup bisection target
#define LCAP 16          // per-lane candidate slots (fills the 32KB union)
#define NFIX 256         // parallel-fixup row capacity

typedef __attribute__((ext_vector_type(8))) short bf16x8;
typedef __attribute__((ext_vector_type(4))) float f32x4;

#define GLD_LDS16(gp, lp)                                                   \
    __builtin_amdgcn_global_load_lds(                                       \
        (const __attribute__((address_space(1))) void*)(uintptr_t)(gp),     \
        (__attribute__((address_space(3))) void*)(uint32_t)(uintptr_t)(lp), \
        16, 0, 0)

__device__ inline short f2bf(float x) {
    unsigned u = __float_as_uint(x);
    return (short)((u + 0x7FFF + ((u >> 16) & 1)) >> 16);
}
__device__ inline float bf2f(short s) {
    return __uint_as_float(((unsigned)(unsigned short)s) << 16);
}

// ---------------------------------------------------------------- prep: bf16 cast + ||f||^2
__global__ __launch_bounds__(64) void prep_kernel(const float* __restrict__ f,
                                                  short* __restrict__ fh,
                                                  float* __restrict__ sq) {
    int row  = blockIdx.x;
    int lane = threadIdx.x;
    float4 v = ((const float4*)(f + (size_t)row * ND))[lane];
    float acc = v.x * v.x + v.y * v.y + v.z * v.z + v.w * v.w;
    *(short4*)(fh + (size_t)row * ND + lane * 4) =
        make_short4(f2bf(v.x), f2bf(v.y), f2bf(v.z), f2bf(v.w));
#pragma unroll
    for (int off = 32; off; off >>= 1) acc += __shfl_down(acc, off);
    if (lane == 0) sq[row] = acc;
}

// ---------------------------------------------------------------- mstat: per-row threshold; zero control state
__global__ __launch_bounds__(256) void mstat_kernel(const float* __restrict__ sq,
                                                    float* __restrict__ T,
                                                    int* __restrict__ cnt,
                                                    int* __restrict__ flagA,
                                                    int* __restrict__ flagB,
                                                    int* __restrict__ nflag) {
    int tid = threadIdx.x;
    __shared__ float r1[4], r2[4];
    float a1 = 0.f, a2 = 0.f;
    for (int t = tid; t < NB; t += 256) { float s = sq[t]; a1 += s; a2 += s * s; }
#pragma unroll
    for (int off = 32; off; off >>= 1) { a1 += __shfl_xor(a1, off); a2 += __shfl_xor(a2, off); }
    if ((tid & 63) == 0) { r1[tid >> 6] = a1; r2[tid >> 6] = a2; }
    __syncthreads();
    float M1 = (r1[0] + r1[1] + r1[2] + r1[3]) * (1.0f / NB);
    float M2 = (r2[0] + r2[1] + r2[2] + r2[3]) * (1.0f / NB);
    float varsq = fmaxf(M2 - M1 * M1, 0.f);
    if (tid == 0) nflag[0] = 0;
    for (int t = tid; t < NB; t += 256) {
        float s = sq[t];
        float sig = sqrtf(varsq + 4.f * s);
        T[t] = s + M1 - 2.0f * sig;              // mu_i - 2*sigma_i
        cnt[t]   = 0;
        flagA[t] = 0;
        flagB[t] = 0;
    }
}

// ---------------------------------------------------------------- MFMA Gram + compressed candidate append
#define BM 128
#define BK 64
__global__ __launch_bounds__(256) void gram_kernel(const short* __restrict__ fh,
                                                   const float* __restrict__ sq,
                                                   const float* __restrict__ T,
                                                   int* __restrict__ cnt,
                                                   int* __restrict__ flagA,
                                                   float2* __restrict__ cand) {
    __shared__ __align__(16) union SMem {
        short ab[2 * BM * BK];                                  // 32 KB staging
        struct { float d[256 * LCAP]; int k[256 * LCAP]; } cb;  // 32 KB slots
    } smem;
    __shared__ float sT[BM];
    short* As = smem.ab;
    short* Bs = smem.ab + BM * BK;

    int b   = blockIdx.x;
    int ti  = (b >> 5) * BM;
    int tj  = (b & 31) * BM;
    int tid = threadIdx.x;
    int w = tid >> 6, lane = tid & 63;
    int wr = w >> 1, wc = w & 1;
    int fr = lane & 15, fq = lane >> 4;

    if (tid < BM) sT[tid] = T[ti + tid];

    f32x4 acc[4][4];
#pragma unroll
    for (int m = 0; m < 4; ++m)
#pragma unroll
        for (int n = 0; n < 4; ++n) acc[m][n] = (f32x4){0.f, 0.f, 0.f, 0.f};

    int srow = lane >> 3;
    int scol = (lane & 7) * 8;

    for (int s = 0; s < 4; ++s) {
        int k0 = s * 64;
#pragma unroll
        for (int i = 0; i < 4; ++i) {
            int c   = 4 * w + i;
            int row = c * 8 + srow;
            GLD_LDS16(fh + (size_t)(ti + row) * ND + k0 + scol, As + c * 512);
            GLD_LDS16(fh + (size_t)(tj + row) * ND + k0 + scol, Bs + c * 512);
        }
        __syncthreads();
#pragma unroll
        for (int kk = 0; kk < 2; ++kk) {
            bf16x8 af[4], bfr[4];
#pragma unroll
            for (int m = 0; m < 4; ++m)
                af[m] = *(const bf16x8*)(As + (wr * 64 + m * 16 + fr) * 64 + kk * 32 + fq * 8);
#pragma unroll
            for (int n = 0; n < 4; ++n)
                bfr[n] = *(const bf16x8*)(Bs + (wc * 64 + n * 16 + fr) * 64 + kk * 32 + fq * 8);
#pragma unroll
            for (int m = 0; m < 4; ++m)
#pragma unroll
                for (int n = 0; n < 4; ++n)
                    acc[m][n] = __builtin_amdgcn_mfma_f32_16x16x32_bf16(af[m], bfr[n], acc[m][n], 0, 0, 0);
        }
        __syncthreads();                          // LDS reads drained -> overlay safe
    }

    // phase 1: filter into per-lane LDS slots
    float* cbd = smem.cb.d;
    int*   cbk = smem.cb.k;
    int nc = 0;
#pragma unroll
    for (int m = 0; m < 4; ++m) {
#pragma unroll
        for (int j = 0; j < 4; ++j) {
            int rl = wr * 64 + m * 16 + fq * 4 + j;
            int gi = ti + rl;
            float si = sq[gi];
            float Tr = sT[rl];
#pragma unroll
            for (int n = 0; n < 4; ++n) {
                int col = tj + wc * 64 + n * 16 + fr;
                float d = fmaxf(si + sq[col] - 2.f * acc[m][n][j], 0.f);
                if (d < Tr) {
                    if (nc < LCAP) {
                        cbd[tid * LCAP + nc] = d;
                        cbk[tid * LCAP + nc] = (rl << 12) | col;
                        ++nc;
                    } else {
                        flagA[gi] = 1;            // lane overflow -> fixup
                    }
                }
            }
        }
    }

    // phase 2: short append loop
    int kmax = nc;
#pragma unroll
    for (int off = 32; off; off >>= 1) kmax = max(kmax, __shfl_xor(kmax, off));
    for (int k = 0; k < kmax; ++k) {
        if (k < nc) {
            float d  = cbd[tid * LCAP + k];
            int  key = cbk[tid * LCAP + k];
            int  gi2 = ti + (key >> 12);
            int  col = key & 4095;
            int pos = atomicAdd(&cnt[gi2], 1);
            if (pos < CAP) cand[(size_t)gi2 * CAP + pos] = make_float2(d, __int_as_float(col));
            else flagA[gi2] = 1;
        }
    }
}

// ---------------------------------------------------------------- topk5: rank-select; failures -> compact flag list
__global__ __launch_bounds__(256) void topk5_kernel(const float2* __restrict__ cand,
                                                    const int* __restrict__ cnt,
                                                    const int* __restrict__ flagA,
                                                    int* __restrict__ flagB,
                                                    int* __restrict__ rowmap,
                                                    int* __restrict__ nflag,
                                                    int* __restrict__ idxk,
                                                    float* __restrict__ dk,
                                                    float* __restrict__ sigma) {
    int wid  = threadIdx.x >> 6;
    int lane = threadIdx.x & 63;
    int row  = blockIdx.x * 4 + wid;
    int c = cnt[row];
    if (flagA[row] || c < NK || c > CAP) {
        if (lane == 0) {
            int slot = atomicAdd(nflag, 1);
            if (slot < NFIX) rowmap[slot] = row;
            else flagB[row] = 1;                  // beyond capacity -> serial fallback
        }
        return;
    }
    int slots = (c + 63) >> 6;

    float v[4]; int id[4];
#pragma unroll
    for (int k = 0; k < 4; ++k) {
        int p = lane + 64 * k;
        if (p < c) {
            float2 q = cand[(size_t)row * CAP + p];
            v[k] = q.x; id[k] = __float_as_int(q.y);
        } else { v[k] = FLT_MAX; id[k] = 0x7fffffff; }
    }
    int rank[4] = {0, 0, 0, 0};
    for (int s = 0; s < 64; ++s) {
        int sl = (lane + s) & 63;
#pragma unroll
        for (int k2 = 0; k2 < 4; ++k2) {
            if (k2 < slots) {
                float y  = __shfl(v[k2], sl);
                int   yi = __shfl(id[k2], sl);
#pragma unroll
                for (int k = 0; k < 4; ++k) {
                    if (k < slots) {
                        bool lt = (y < v[k]) || (y == v[k] && yi < id[k]);
                        rank[k] += lt ? 1 : 0;
                    }
                }
            }
        }
    }
    float t = 0.f;
#pragma unroll
    for (int k = 0; k < 4; ++k) {
        if (k < slots && v[k] != FLT_MAX && rank[k] < NK) {
            idxk[row * NK + rank[k]] = id[k];
            dk[row * NK + rank[k]]   = v[k];
            t += sqrtf(v[k] + EPSF);
        }
    }
#pragma unroll
    for (int off = 32; off; off >>= 1) t += __shfl_xor(t, off);
    if (lane == 0) sigma[row] = t * (1.0f / NK);
}

// ---------------------------------------------------------------- fgemv: parallel exact distances for flagged rows
__global__ __launch_bounds__(256) void fgemv_kernel(const short* __restrict__ fh,
                                                    const float* __restrict__ sq,
                                                    const int* __restrict__ rowmap,
                                                    const int* __restrict__ nflag,
                                                    float* __restrict__ dfix) {
    int b = blockIdx.x;
    int fi = b >> 4, chunk = b & 15;
    int nf = min(nflag[0], NFIX);
    if (fi >= nf) return;
    int row = rowmap[fi];
    __shared__ __align__(16) float frv[ND];
    int tid = threadIdx.x;
    frv[tid] = bf2f(fh[(size_t)row * ND + tid]);
    __syncthreads();
    int col = chunk * 256 + tid;
    const short4* fc4 = (const short4*)(fh + (size_t)col * ND);
    float acc = 0.f;
#pragma unroll 8
    for (int a4 = 0; a4 < ND / 4; ++a4) {
        short4 q  = fc4[a4];
        float4 fv = *(const float4*)&frv[a4 * 4];
        acc += fv.x * bf2f(q.x) + fv.y * bf2f(q.y)
             + fv.z * bf2f(q.z) + fv.w * bf2f(q.w);
    }
    dfix[(size_t)fi * NB + col] = fmaxf(sq[row] + sq[col] - 2.f * acc, 0.f);
}

// ---------------------------------------------------------------- fselect: exact top-25 on dense fixup rows (parallel)
__global__ __launch_bounds__(256) void fselect_kernel(const float* __restrict__ dfix,
                                                      const int* __restrict__ rowmap,
                                                      const int* __restrict__ nflag,
                                                      int* __restrict__ idxk,
                                                      float* __restrict__ dk,
                                                      float* __restrict__ sigma) {
    int fi = blockIdx.x;
    int nf = min(nflag[0], NFIX);
    if (fi >= nf) return;
    int row = rowmap[fi];
    __shared__ float rowv[NB];
    __shared__ float cval[CAP_FB];
    __shared__ int   cidx[CAP_FB];
    __shared__ int   red[4];
    __shared__ float redf[4];
    __shared__ int   s_cnt;
    int tid = threadIdx.x;

    for (int t = tid; t < NB / 4; t += 256) {
        float4 q = ((const float4*)(dfix + (size_t)fi * NB))[t];
        rowv[t * 4 + 0] = q.x; rowv[t * 4 + 1] = q.y;
        rowv[t * 4 + 2] = q.z; rowv[t * 4 + 3] = q.w;
    }
    __syncthreads();

    float mx = 0.f;
    for (int t = tid; t < NB; t += 256) mx = fmaxf(mx, rowv[t]);
#pragma unroll
    for (int off = 32; off; off >>= 1) mx = fmaxf(mx, __shfl_xor(mx, off));
    if ((tid & 63) == 0) redf[tid >> 6] = mx;
    __syncthreads();
    mx = fmaxf(fmaxf(redf[0], redf[1]), fmaxf(redf[2], redf[3]));

    unsigned lo = 0u, hi = __float_as_uint(mx) + 1u;
    int cnt_hi = NB;
    for (int it = 0; it < 34; ++it) {
        if (cnt_hi <= CTGT || hi <= lo + 1u) break;
        unsigned mid = (lo + hi) >> 1;
        float Tm = __uint_as_float(mid);
        int c = 0;
        for (int t = tid; t < NB; t += 256) c += (rowv[t] < Tm) ? 1 : 0;
#pragma unroll
        for (int off = 32; off; off >>= 1) c += __shfl_xor(c, off);
        __syncthreads();
        if ((tid & 63) == 0) red[tid >> 6] = c;
        __syncthreads();
        c = red[0] + red[1] + red[2] + red[3];
        if (c >= NK) { hi = mid; cnt_hi = c; } else { lo = mid; }
    }
    float Thi = __uint_as_float(hi);
    if (tid == 0) s_cnt = 0;
    __syncthreads();
    for (int t = tid; t < NB; t += 256) {
        if (rowv[t] < Thi) {
            int p = atomicAdd(&s_cnt, 1);
            if (p < CAP_FB) { cval[p] = rowv[t]; cidx[p] = t; }
        }
    }
    __syncthreads();
    int cnt = min(s_cnt, CAP_FB);

    if (tid < 64) {
        float ssum = 0.f;
        for (int it = 0; it < NK; ++it) {
            float bv = FLT_MAX; int bi = NB; int bp = -1;
            for (int r = tid; r < cnt; r += 64) {
                float cv = cval[r]; int ci = cidx[r];
                if (cv < bv || (cv == bv && ci < bi)) { bv = cv; bi = ci; bp = r; }
            }
#pragma unroll
            for (int off = 32; off; off >>= 1) {
                float ov = __shfl_down(bv, off);
                int   oi = __shfl_down(bi, off);
                int   op = __shfl_down(bp, off);
                if (ov < bv || (ov == bv && oi < bi)) { bv = ov; bi = oi; bp = op; }
            }
            bp = __shfl(bp, 0); bv = __shfl(bv, 0); bi = __shfl(bi, 0);
            if (tid == 0) {
                idxk[row * NK + it] = bi;
                dk[row * NK + it]   = bv;
                cval[bp] = FLT_MAX;
            }
            ssum += sqrtf(bv + EPSF);
        }
        if (tid == 0) sigma[row] = ssum * (1.0f / NK);
    }
}

// ---------------------------------------------------------------- serial fallback (slot >= NFIX; ~never)
__global__ __launch_bounds__(256) void fserial_kernel(const short* __restrict__ fh,
                                                      const float* __restrict__ sq,
                                                      const int* __restrict__ flagB,
                                                      int* __restrict__ idxk,
                                                      float* __restrict__ dk,
                                                      float* __restrict__ sigma) {
    int row = blockIdx.x;
    if (flagB[row] == 0) return;
    __shared__ float rowv[NB];
    __shared__ __align__(16) float frv[ND];
    __shared__ float cval[CAP_FB];
    __shared__ int   cidx[CAP_FB];
    __shared__ int   red[4];
    __shared__ float redf[4];
    __shared__ int   s_cnt;
    int tid = threadIdx.x;

    for (int a = tid; a < ND; a += 256) frv[a] = bf2f(fh[(size_t)row * ND + a]);
    __syncthreads();
    float sqr = sq[row];
    for (int c = tid; c < NB; c += 256) {
        const short4* fc4 = (const short4*)(fh + (size_t)c * ND);
        float acc = 0.f;
#pragma unroll 8
        for (int a4 = 0; a4 < ND / 4; ++a4) {
            short4 q  = fc4[a4];
            float4 fv = *(const float4*)&frv[a4 * 4];
            acc += fv.x * bf2f(q.x) + fv.y * bf2f(q.y)
                 + fv.z * bf2f(q.z) + fv.w * bf2f(q.w);
        }
        rowv[c] = fmaxf(sqr + sq[c] - 2.f * acc, 0.f);
    }
    __syncthreads();

    float mx = 0.f;
    for (int t = tid; t < NB; t += 256) mx = fmaxf(mx, rowv[t]);
#pragma unroll
    for (int off = 32; off; off >>= 1) mx = fmaxf(mx, __shfl_xor(mx, off));
    if ((tid & 63) == 0) redf[tid >> 6] = mx;
    __syncthreads();
    mx = fmaxf(fmaxf(redf[0], redf[1]), fmaxf(redf[2], redf[3]));

    unsigned lo = 0u, hi = __float_as_uint(mx) + 1u;
    int cnt_hi = NB;
    for (int it = 0; it < 34; ++it) {
        if (cnt_hi <= CTGT || hi <= lo + 1u) break;
        unsigned mid = (lo + hi) >> 1;
        float Tm = __uint_as_float(mid);
        int c = 0;
        for (int t = tid; t < NB; t += 256) c += (rowv[t] < Tm) ? 1 : 0;
#pragma unroll
        for (int off = 32; off; off >>= 1) c += __shfl_xor(c, off);
        __syncthreads();
        if ((tid & 63) == 0) red[tid >> 6] = c;
        __syncthreads();
        c = red[0] + red[1] + red[2] + red[3];
        if (c >= NK) { hi = mid; cnt_hi = c; } else { lo = mid; }
    }
    float Thi = __uint_as_float(hi);
    if (tid == 0) s_cnt = 0;
    __syncthreads();
    for (int t = tid; t < NB; t += 256) {
        if (rowv[t] < Thi) {
            int p = atomicAdd(&s_cnt, 1);
            if (p < CAP_FB) { cval[p] = rowv[t]; cidx[p] = t; }
        }
    }
    __syncthreads();
    int cnt = min(s_cnt, CAP_FB);

    if (tid < 64) {
        float ssum = 0.f;
        for (int it = 0; it < NK; ++it) {
            float bv = FLT_MAX; int bi = NB; int bp = -1;
            for (int r = tid; r < cnt; r += 64) {
                float cv = cval[r]; int ci = cidx[r];
                if (cv < bv || (cv == bv && ci < bi)) { bv = cv; bi = ci; bp = r; }
            }
#pragma unroll
            for (int off = 32; off; off >>= 1) {
                float ov = __shfl_down(bv, off);
                int   oi = __shfl_down(bi, off);
                int   op = __shfl_down(bp, off);
                if (ov < bv || (ov == bv && oi < bi)) { bv = ov; bi = oi; bp = op; }
            }
            bp = __shfl(bp, 0); bv = __shfl(bv, 0); bi = __shfl(bi, 0);
            if (tid == 0) {
                idxk[row * NK + it] = bi;
                dk[row * NK + it]   = bv;
                cval[bp] = FLT_MAX;
            }
            ssum += sqrtf(bv + EPSF);
        }
        if (tid == 0) sigma[row] = ssum * (1.0f / NK);
    }
}

// ---------------------------------------------------------------- P rows + score-sorted prefix tables
__global__ __launch_bounds__(64) void buildp_kernel(const int* __restrict__ idxk,
                                                    const float* __restrict__ dk,
                                                    const float* __restrict__ sigma,
                                                    const int* __restrict__ labels,
                                                    const float* __restrict__ scores,
                                                    float* __restrict__ pval,
                                                    float* __restrict__ bs,
                                                    float2* __restrict__ cs) {
    int row  = blockIdx.x;
    int lane = threadIdx.x;
    __shared__ float sb[32];
    __shared__ float sp[32];

    float w = 0.f;
    int j = 0;
    if (lane < NK) {
        j = idxk[row * NK + lane];
        bool mut = false;
        for (int n = 0; n < NK; ++n) mut |= (idxk[j * NK + n] == row);
        bool dir = labels[row] <= labels[j];
        float sij = sigma[row] * sigma[j] + EPSF;
        w = (mut && dir) ? expf(-dk[row * NK + lane] / sij) : 0.f;
        if (j == row) w += 1.f;
    }
    float rs = w;
#pragma unroll
    for (int off = 32; off; off >>= 1) rs += __shfl_down(rs, off);
    rs = __shfl(rs, 0);
    float pv = (lane < NK) ? w / (rs + EPSF) : 0.f;
    if (lane < NK) pval[row * NK + lane] = pv;

    float sj = (lane < NK) ? scores[j] : FLT_MAX;
    int rank = 0;
#pragma unroll
    for (int u = 0; u < NK; ++u) {
        float su = __shfl(sj, u);
        rank += (su < sj || (su == sj && u < lane)) ? 1 : 0;
    }
    if (lane < 32) { sb[lane] = FLT_MAX; sp[lane] = 0.f; }
    __syncthreads();
    if (lane < NK) { sb[rank] = sj; sp[rank] = pv; }
    __syncthreads();

    float b = sb[lane & 31];
    float p = sp[lane & 31];
    float c  = p;
    float s2 = p * b;
#pragma unroll
    for (int off = 1; off < 32; off <<= 1) {
        float oc = __shfl_up(c, off);
        float os = __shfl_up(s2, off);
        if (lane >= off) { c += oc; s2 += os; }
    }
    float ce = __shfl_up(c, 1);
    float se = __shfl_up(s2, 1);
    if (lane == 0) { ce = 0.f; se = 0.f; }
    if (lane < 32) {
        bs[row * 32 + lane] = b;
        cs[row * 32 + lane] = make_float2(ce, se);
    }
}

// ---------------------------------------------------------------- hval: per-j G/H at the 25 needed points
__global__ __launch_bounds__(256) void hval_kernel(const int* __restrict__ idxk,
                                                   const float* __restrict__ pval,
                                                   const float* __restrict__ scores,
                                                   const float* __restrict__ bs,
                                                   const float2* __restrict__ cs,
                                                   float* __restrict__ Gval,
                                                   float* __restrict__ Hval) {
    int wid  = threadIdx.x >> 6;
    int lane = threadIdx.x & 63;
    int j    = blockIdx.x * 4 + wid;
    __shared__ float2 slab[4][NK][26];

    int  ln = (lane < NK) ? lane : NK - 1;
    int  q  = idxk[j * NK + ln];
    float p = (lane < NK) ? pval[j * NK + lane] : 0.f;
    float sqv = scores[q];

    float4 bq[7];
    const float4* b4 = (const float4*)(bs + q * 32);
#pragma unroll
    for (int t = 0; t < 7; ++t) bq[t] = b4[t];
    const float4* c4 = (const float4*)(cs + q * 32);
    if (lane < NK) {
#pragma unroll
        for (int t = 0; t < 13; ++t)
            *(float4*)&slab[wid][lane][t * 2] = c4[t];
    }

    float bjj = bs[j * 32 + lane];
    int posj = 0;
#pragma unroll
    for (int r = 0; r < NK; ++r)
        posj += (__shfl(bjj, r) < sqv) ? 1 : 0;
    float2 cj = cs[j * 32 + posj];
    if (lane < NK) Gval[j * 32 + lane] = sqv * cj.x - cj.y;

    __syncthreads();

    for (int u = 0; u < NK; ++u) {
        float x = __shfl(sqv, u);
        int pos = 0;
#pragma unroll
        for (int t = 0; t < 7; ++t) {
            float4 b = bq[t];
            pos += (b.x < x) + (b.y < x) + (b.z < x) + (b.w < x);
        }
        float2 ch = slab[wid][ln][pos];
        float g = p * (x * ch.x - ch.y);
#pragma unroll
        for (int off = 32; off; off >>= 1) g += __shfl_xor(g, off);
        if (lane == 0) Hval[j * 32 + u] = g;
    }
}

// ---------------------------------------------------------------- final loss: per-wave partial
__global__ __launch_bounds__(256) void loss_kernel(const float* __restrict__ scores,
                                                   const int* __restrict__ idxk,
                                                   const float* __restrict__ pval,
                                                   const float* __restrict__ Gval,
                                                   const float* __restrict__ Hval,
                                                   float* __restrict__ partial) {
    int wid  = threadIdx.x >> 6;
    int lane = threadIdx.x & 63;
    int i    = blockIdx.x * 4 + wid;
    float si = scores[i];
    float acc = 0.f;
    if (lane < NK) {
        int   jm = idxk[i * NK + lane];
        float pm = pval[i * NK + lane];
        float sj = scores[jm];
        int slot = -1;
        const int* row = idxk + jm * NK;
#pragma unroll
        for (int n = 0; n < NK; ++n)
            if (row[n] == i) slot = n;
        float g = 0.f, h = 0.f;
        if (slot >= 0) {
            g = Gval[jm * 32 + slot];
            h = Hval[jm * 32 + slot];
        }
        acc = pm * (fmaxf(si - sj, 0.f) + 0.5f * g + (1.f / 3.f) * h);
    }
#pragma unroll
    for (int off = 32; off; off >>= 1) acc += __shfl_xor(acc, off);
    if (lane == 0) partial[i] = acc;
}

// ---------------------------------------------------------------- final reduce
__global__ __launch_bounds__(256) void reduce_kernel(const float* __restrict__ partial,
                                                     float* __restrict__ out) {
    int tid = threadIdx.x;
    __shared__ float red[4];
    float a = 0.f;
    for (int t = tid; t < NB / 4; t += 256) {
        float4 p = ((const float4*)partial)[t];
        a += p.x + p.y + p.z + p.w;
    }
#pragma unroll
    for (int off = 32; off; off >>= 1) a += __shfl_xor(a, off);
    if ((tid & 63) == 0) red[tid >> 6] = a;
    __syncthreads();
    if (tid == 0) out[0] = (red[0] + red[1] + red[2] + red[3]) * (1.0f / NB);
}

// ---------------------------------------------------------------- launch
extern "C" void kernel_launch(void* const* d_in, const int* in_sizes, int n_in,
                              void* d_out, int out_size, void* d_ws, size_t ws_size,
                              hipStream_t stream) {
    const float* features = (const float*)d_in[0];
    const float* scores   = (const float*)d_in[1];
    const int*   labels   = (const int*)d_in[2];
    float* out = (float*)d_out;

    char* ws = (char*)d_ws;
    size_t off = 0;
    float2* cand    = (float2*)(ws + off); off += (size_t)NB * CAP * 8;     // 8 MB
    float*  dfix    = (float*) (ws + off); off += (size_t)NFIX * NB * 4;    // 4 MB
    short*  fh      = (short*) (ws + off); off += (size_t)NB * ND * 2;      // 2 MB
    float*  sq      = (float*) (ws + off); off += (size_t)NB * 4;
    float*  T       = (float*) (ws + off); off += (size_t)NB * 4;
    int*    cnt     = (int*)   (ws + off); off += (size_t)NB * 4;
    int*    flagA   = (int*)   (ws + off); off += (size_t)NB * 4;
    int*    flagB   = (int*)   (ws + off); off += (size_t)NB * 4;
    int*    rowmap  = (int*)   (ws + off); off += (size_t)NFIX * 4;
    int*    nflag   = (int*)   (ws + off); off += 64;
    int*    idxk    = (int*)   (ws + off); off += (size_t)NB * NK * 4;
    float*  dk      = (float*) (ws + off); off += (size_t)NB * NK * 4;
    float*  sigma   = (float*) (ws + off); off += (size_t)NB * 4;
    float*  pval    = (float*) (ws + off); off += (size_t)NB * NK * 4;
    float*  bs      = (float*) (ws + off); off += (size_t)NB * 32 * 4;
    float2* cs      = (float2*)(ws + off); off += (size_t)NB * 32 * 8;
    float*  Gval    = (float*) (ws + off); off += (size_t)NB * 32 * 4;
    float*  Hval    = (float*) (ws + off); off += (size_t)NB * 32 * 4;
    float*  partial = (float*) (ws + off); off += (size_t)NB * 4;

    prep_kernel<<<NB, 64, 0, stream>>>(features, fh, sq);
    mstat_kernel<<<1, 256, 0, stream>>>(sq, T, cnt, flagA, flagB, nflag);
    gram_kernel<<<(NB / BM) * (NB / BM), 256, 0, stream>>>(fh, sq, T, cnt, flagA, cand);
    topk5_kernel<<<NB / 4, 256, 0, stream>>>(cand, cnt, flagA, flagB, rowmap, nflag, idxk, dk, sigma);
    fgemv_kernel<<<NFIX * 16, 256, 0, stream>>>(fh, sq, rowmap, nflag, dfix);
    fselect_kernel<<<NFIX, 256, 0, stream>>>(dfix, rowmap, nflag, idxk, dk, sigma);
    fserial_kernel<<<NB, 256, 0, stream>>>(fh, sq, flagB, idxk, dk, sigma);
    buildp_kernel<<<NB, 64, 0, stream>>>(idxk, dk, sigma, labels, scores, pval, bs, cs);
    hval_kernel<<<NB / 4, 256, 0, stream>>>(idxk, pval, scores, bs, cs, Gval, Hval);
    loss_kernel<<<NB / 4, 256, 0, stream>>>(scores, idxk, pval, Gval, Hval, partial);
    reduce_kernel<<<1, 256, 0, stream>>>(partial, out);
}

// Round 14
// 117.483 us; speedup vs baseline: 2.0571x; 1.5745x over previous
//
#include <hip/hip_runtime.h>
#include <math.h>
#include <float.h>

#define NB 4096
#define ND 256
#define NK 25
#define EPSF 1e-8f
#define CAP 256          // candidate capacity (4 slots/lane)

typedef __attribute__((ext_vector_type(8))) short bf16x8;
typedef __attribute__((ext_vector_type(4))) float f32x4;

#define GLD_LDS16(gp, lp)                                                   \
    __builtin_amdgcn_global_load_lds(                                       \
        (const __attribute__((address_space(1))) void*)(uintptr_t)(gp),     \
        (__attribute__((address_space(3))) void*)(uint32_t)(uintptr_t)(lp), \
        16, 0, 0)

__device__ inline short f2bf(float x) {
    unsigned u = __float_as_uint(x);
    return (short)((u + 0x7FFF + ((u >> 16) & 1)) >> 16);
}

// ---------------------------------------------------------------- prep: bf16 cast + ||f||^2
__global__ __launch_bounds__(64) void prep_kernel(const float* __restrict__ f,
                                                  short* __restrict__ fh,
                                                  float* __restrict__ sq) {
    int row  = blockIdx.x;
    int lane = threadIdx.x;
    float4 v = ((const float4*)(f + (size_t)row * ND))[lane];
    float acc = v.x * v.x + v.y * v.y + v.z * v.z + v.w * v.w;
    *(short4*)(fh + (size_t)row * ND + lane * 4) =
        make_short4(f2bf(v.x), f2bf(v.y), f2bf(v.z), f2bf(v.w));
#pragma unroll
    for (int off = 32; off; off >>= 1) acc += __shfl_down(acc, off);
    if (lane == 0) sq[row] = acc;
}

// ---------------------------------------------------------------- MFMA Gram (hi-only, K=256) + dist epilogue (R8)
#define BM 128
#define BK 64
__global__ __launch_bounds__(256) void gram_kernel(const short* __restrict__ fh,
                                                   const float* __restrict__ sq,
                                                   float* __restrict__ dist) {
    __shared__ __align__(16) short As[BM * BK];
    __shared__ __align__(16) short Bs[BM * BK];
    int b   = blockIdx.x;
    int ti  = (b >> 5) * BM;
    int tj  = (b & 31) * BM;
    int tid = threadIdx.x;
    int w = tid >> 6, lane = tid & 63;
    int wr = w >> 1, wc = w & 1;
    int fr = lane & 15, fq = lane >> 4;

    f32x4 acc[4][4];
#pragma unroll
    for (int m = 0; m < 4; ++m)
#pragma unroll
        for (int n = 0; n < 4; ++n) acc[m][n] = (f32x4){0.f, 0.f, 0.f, 0.f};

    int srow = lane >> 3;
    int scol = (lane & 7) * 8;

    for (int s = 0; s < 4; ++s) {
        int k0 = s * 64;
#pragma unroll
        for (int i = 0; i < 4; ++i) {
            int c   = 4 * w + i;
            int row = c * 8 + srow;
            GLD_LDS16(fh + (size_t)(ti + row) * ND + k0 + scol, As + c * 512);
            GLD_LDS16(fh + (size_t)(tj + row) * ND + k0 + scol, Bs + c * 512);
        }
        __syncthreads();
#pragma unroll
        for (int kk = 0; kk < 2; ++kk) {
            bf16x8 af[4], bfr[4];
#pragma unroll
            for (int m = 0; m < 4; ++m)
                af[m] = *(const bf16x8*)(As + (wr * 64 + m * 16 + fr) * 64 + kk * 32 + fq * 8);
#pragma unroll
            for (int n = 0; n < 4; ++n)
                bfr[n] = *(const bf16x8*)(Bs + (wc * 64 + n * 16 + fr) * 64 + kk * 32 + fq * 8);
#pragma unroll
            for (int m = 0; m < 4; ++m)
#pragma unroll
                for (int n = 0; n < 4; ++n)
                    acc[m][n] = __builtin_amdgcn_mfma_f32_16x16x32_bf16(af[m], bfr[n], acc[m][n], 0, 0, 0);
        }
        __syncthreads();
    }

#pragma unroll
    for (int m = 0; m < 4; ++m) {
#pragma unroll
        for (int j = 0; j < 4; ++j) {
            int gi = ti + wr * 64 + m * 16 + fq * 4 + j;
            float si = sq[gi];
            float* drow = dist + (size_t)gi * NB + tj + wc * 64;
#pragma unroll
            for (int n = 0; n < 4; ++n) {
                float d = si + sq[tj + wc * 64 + n * 16 + fr] - 2.f * acc[m][n][j];
                drow[n * 16 + fr] = fmaxf(d, 0.f);
            }
        }
    }
}

// ---------------------------------------------------------------- topk6: wave/row, row-stat threshold, rank-select
// T = mu_row - 2*sd_row (expected ~93 survivors; rank-25 at z~-2.5).
// One count pass; bisection only as in-wave fallback (prob ~0).
__global__ __launch_bounds__(256) void topk6_kernel(const float* __restrict__ dist,
                                                    int* __restrict__ idxk,
                                                    float* __restrict__ dk,
                                                    float* __restrict__ sigma) {
    int wid  = threadIdx.x >> 6;
    int lane = threadIdx.x & 63;
    int row  = blockIdx.x * 4 + wid;
    __shared__ float cval[4][CAP];
    __shared__ int   cidx[4][CAP];

    float v[64];
    const float4* src = (const float4*)(dist + (size_t)row * NB);
#pragma unroll
    for (int c4 = 0; c4 < 16; ++c4) {
        float4 q = src[c4 * 64 + lane];
        v[c4 * 4 + 0] = q.x; v[c4 * 4 + 1] = q.y;
        v[c4 * 4 + 2] = q.z; v[c4 * 4 + 3] = q.w;
    }

    // row stats: mean, var, max
    float s1 = 0.f, s2 = 0.f, mx = v[0];
#pragma unroll
    for (int e = 0; e < 64; ++e) {
        float x = v[e];
        s1 += x; s2 += x * x; mx = fmaxf(mx, x);
    }
#pragma unroll
    for (int off = 32; off; off >>= 1) {
        s1 += __shfl_xor(s1, off);
        s2 += __shfl_xor(s2, off);
        mx  = fmaxf(mx, __shfl_xor(mx, off));
    }
    float mu = s1 * (1.0f / NB);
    float sd = sqrtf(fmaxf(s2 * (1.0f / NB) - mu * mu, 0.f));
    float T  = mu - 2.0f * sd;

    int c = 0;
#pragma unroll
    for (int e = 0; e < 64; ++e) c += (v[e] < T) ? 1 : 0;
#pragma unroll
    for (int off = 32; off; off >>= 1) c += __shfl_xor(c, off);

    if (c < NK || c > CAP) {
        // fallback: mean-seeded bisection to count in [NK, CAP]
        float lo = 0.f, hi = mu;
        int cnt_hi = 0;
#pragma unroll
        for (int e = 0; e < 64; ++e) cnt_hi += (v[e] < mu) ? 1 : 0;
#pragma unroll
        for (int off = 32; off; off >>= 1) cnt_hi += __shfl_xor(cnt_hi, off);
        if (cnt_hi < NK) { hi = mx * 1.000001f + 1e-20f; cnt_hi = NB; }
        for (int it = 0; it < 40; ++it) {
            if (cnt_hi <= CAP) break;
            float mid = 0.5f * (lo + hi);
            if (mid <= lo || mid >= hi) break;
            int cc = 0;
#pragma unroll
            for (int e = 0; e < 64; ++e) cc += (v[e] < mid) ? 1 : 0;
#pragma unroll
            for (int off = 32; off; off >>= 1) cc += __shfl_xor(cc, off);
            if (cc >= NK) { hi = mid; cnt_hi = cc; } else { lo = mid; }
        }
        T = hi; c = cnt_hi;
    }

    // ballot/popc compaction of candidates < T
    unsigned long long ltmask = (1ull << lane) - 1ull;
    int cnt = 0;
#pragma unroll
    for (int e = 0; e < 64; ++e) {
        bool p = (v[e] < T);
        unsigned long long m = __ballot(p);
        if (p) {
            int pos = cnt + __popcll(m & ltmask);
            if (pos < CAP) {
                cval[wid][pos] = v[e];
                cidx[wid][pos] = ((e >> 2) * 64 + lane) * 4 + (e & 3);
            }
        }
        cnt += __popcll(m);
    }
    cnt = min(cnt, CAP);

    // exact rank-select: rank by (value,index) over <=256 candidates, 4 slots/lane
    int slots = (cnt + 63) >> 6;
    float x[4]; int xi[4];
#pragma unroll
    for (int k = 0; k < 4; ++k) {
        int p = lane + 64 * k;
        if (p < cnt) { x[k] = cval[wid][p]; xi[k] = cidx[wid][p]; }
        else         { x[k] = FLT_MAX;      xi[k] = 0x7fffffff; }
    }
    int rank[4] = {0, 0, 0, 0};
    for (int s = 0; s < 64; ++s) {
        int sl = (lane + s) & 63;
#pragma unroll
        for (int k2 = 0; k2 < 4; ++k2) {
            if (k2 < slots) {
                float y  = __shfl(x[k2], sl);
                int   yi = __shfl(xi[k2], sl);
#pragma unroll
                for (int k = 0; k < 4; ++k) {
                    if (k < slots) {
                        bool lt = (y < x[k]) || (y == x[k] && yi < xi[k]);
                        rank[k] += lt ? 1 : 0;
                    }
                }
            }
        }
    }
    float t = 0.f;
#pragma unroll
    for (int k = 0; k < 4; ++k) {
        if (k < slots && x[k] != FLT_MAX && rank[k] < NK) {
            idxk[row * NK + rank[k]] = xi[k];
            dk[row * NK + rank[k]]   = x[k];
            t += sqrtf(x[k] + EPSF);
        }
    }
#pragma unroll
    for (int off = 32; off; off >>= 1) t += __shfl_xor(t, off);
    if (lane == 0) sigma[row] = t * (1.0f / NK);
}

// ---------------------------------------------------------------- P rows + score-sorted prefix tables
__global__ __launch_bounds__(64) void buildp_kernel(const int* __restrict__ idxk,
                                                    const float* __restrict__ dk,
                                                    const float* __restrict__ sigma,
                                                    const int* __restrict__ labels,
                                                    const float* __restrict__ scores,
                                                    float* __restrict__ pval,
                                                    float* __restrict__ bs,
                                                    float2* __restrict__ cs) {
    int row  = blockIdx.x;
    int lane = threadIdx.x;
    __shared__ float sb[32];
    __shared__ float sp[32];

    float w = 0.f;
    int j = 0;
    if (lane < NK) {
        j = idxk[row * NK + lane];
        bool mut = false;
        for (int n = 0; n < NK; ++n) mut |= (idxk[j * NK + n] == row);
        bool dir = labels[row] <= labels[j];
        float sij = sigma[row] * sigma[j] + EPSF;
        w = (mut && dir) ? expf(-dk[row * NK + lane] / sij) : 0.f;
        if (j == row) w += 1.f;
    }
    float rs = w;
#pragma unroll
    for (int off = 32; off; off >>= 1) rs += __shfl_down(rs, off);
    rs = __shfl(rs, 0);
    float pv = (lane < NK) ? w / (rs + EPSF) : 0.f;
    if (lane < NK) pval[row * NK + lane] = pv;

    float sj = (lane < NK) ? scores[j] : FLT_MAX;
    int rank = 0;
#pragma unroll
    for (int u = 0; u < NK; ++u) {
        float su = __shfl(sj, u);
        rank += (su < sj || (su == sj && u < lane)) ? 1 : 0;
    }
    if (lane < 32) { sb[lane] = FLT_MAX; sp[lane] = 0.f; }
    __syncthreads();
    if (lane < NK) { sb[rank] = sj; sp[rank] = pv; }
    __syncthreads();

    float b = sb[lane & 31];
    float p = sp[lane & 31];
    float c  = p;
    float s2 = p * b;
#pragma unroll
    for (int off = 1; off < 32; off <<= 1) {
        float oc = __shfl_up(c, off);
        float os = __shfl_up(s2, off);
        if (lane >= off) { c += oc; s2 += os; }
    }
    float ce = __shfl_up(c, 1);
    float se = __shfl_up(s2, 1);
    if (lane == 0) { ce = 0.f; se = 0.f; }
    if (lane < 32) {
        bs[row * 32 + lane] = b;
        cs[row * 32 + lane] = make_float2(ce, se);
    }
}

// ---------------------------------------------------------------- hval: per-j G/H at the 25 needed points
__global__ __launch_bounds__(256) void hval_kernel(const int* __restrict__ idxk,
                                                   const float* __restrict__ pval,
                                                   const float* __restrict__ scores,
                                                   const float* __restrict__ bs,
                                                   const float2* __restrict__ cs,
                                                   float* __restrict__ Gval,
                                                   float* __restrict__ Hval) {
    int wid  = threadIdx.x >> 6;
    int lane = threadIdx.x & 63;
    int j    = blockIdx.x * 4 + wid;
    __shared__ float2 slab[4][NK][26];

    int  ln = (lane < NK) ? lane : NK - 1;
    int  q  = idxk[j * NK + ln];
    float p = (lane < NK) ? pval[j * NK + lane] : 0.f;
    float sqv = scores[q];

    float4 bq[7];
    const float4* b4 = (const float4*)(bs + q * 32);
#pragma unroll
    for (int t = 0; t < 7; ++t) bq[t] = b4[t];
    const float4* c4 = (const float4*)(cs + q * 32);
    if (lane < NK) {
#pragma unroll
        for (int t = 0; t < 13; ++t)
            *(float4*)&slab[wid][lane][t * 2] = c4[t];
    }

    float bjj = bs[j * 32 + lane];
    int posj = 0;
#pragma unroll
    for (int r = 0; r < NK; ++r)
        posj += (__shfl(bjj, r) < sqv) ? 1 : 0;
    float2 cj = cs[j * 32 + posj];
    if (lane < NK) Gval[j * 32 + lane] = sqv * cj.x - cj.y;

    __syncthreads();

    for (int u = 0; u < NK; ++u) {
        float x = __shfl(sqv, u);
        int pos = 0;
#pragma unroll
        for (int t = 0; t < 7; ++t) {
            float4 b = bq[t];
            pos += (b.x < x) + (b.y < x) + (b.z < x) + (b.w < x);
        }
        float2 ch = slab[wid][ln][pos];
        float g = p * (x * ch.x - ch.y);
#pragma unroll
        for (int off = 32; off; off >>= 1) g += __shfl_xor(g, off);
        if (lane == 0) Hval[j * 32 + u] = g;
    }
}

// ---------------------------------------------------------------- final loss: per-wave partial
__global__ __launch_bounds__(256) void loss_kernel(const float* __restrict__ scores,
                                                   const int* __restrict__ idxk,
                                                   const float* __restrict__ pval,
                                                   const float* __restrict__ Gval,
                                                   const float* __restrict__ Hval,
                                                   float* __restrict__ partial) {
    int wid  = threadIdx.x >> 6;
    int lane = threadIdx.x & 63;
    int i    = blockIdx.x * 4 + wid;
    float si = scores[i];
    float acc = 0.f;
    if (lane < NK) {
        int   jm = idxk[i * NK + lane];
        float pm = pval[i * NK + lane];
        float sj = scores[jm];
        int slot = -1;
        const int* row = idxk + jm * NK;
#pragma unroll
        for (int n = 0; n < NK; ++n)
            if (row[n] == i) slot = n;
        float g = 0.f, h = 0.f;
        if (slot >= 0) {
            g = Gval[jm * 32 + slot];
            h = Hval[jm * 32 + slot];
        }
        acc = pm * (fmaxf(si - sj, 0.f) + 0.5f * g + (1.f / 3.f) * h);
    }
#pragma unroll
    for (int off = 32; off; off >>= 1) acc += __shfl_xor(acc, off);
    if (lane == 0) partial[i] = acc;
}

// ---------------------------------------------------------------- final reduce
__global__ __launch_bounds__(256) void reduce_kernel(const float* __restrict__ partial,
                                                     float* __restrict__ out) {
    int tid = threadIdx.x;
    __shared__ float red[4];
    float a = 0.f;
    for (int t = tid; t < NB / 4; t += 256) {
        float4 p = ((const float4*)partial)[t];
        a += p.x + p.y + p.z + p.w;
    }
#pragma unroll
    for (int off = 32; off; off >>= 1) a += __shfl_xor(a, off);
    if ((tid & 63) == 0) red[tid >> 6] = a;
    __syncthreads();
    if (tid == 0) out[0] = (red[0] + red[1] + red[2] + red[3]) * (1.0f / NB);
}

// ---------------------------------------------------------------- launch
extern "C" void kernel_launch(void* const* d_in, const int* in_sizes, int n_in,
                              void* d_out, int out_size, void* d_ws, size_t ws_size,
                              hipStream_t stream) {
    const float* features = (const float*)d_in[0];
    const float* scores   = (const float*)d_in[1];
    const int*   labels   = (const int*)d_in[2];
    float* out = (float*)d_out;

    char* ws = (char*)d_ws;
    size_t off = 0;
    float*  dist    = (float*) (ws + off); off += (size_t)NB * NB * 4;   // 64 MB
    short*  fh      = (short*) (ws + off); off += (size_t)NB * ND * 2;   // 2 MB
    float*  sq      = (float*) (ws + off); off += (size_t)NB * 4;
    int*    idxk    = (int*)   (ws + off); off += (size_t)NB * NK * 4;
    float*  dk      = (float*) (ws + off); off += (size_t)NB * NK * 4;
    float*  sigma   = (float*) (ws + off); off += (size_t)NB * 4;
    float*  pval    = (float*) (ws + off); off += (size_t)NB * NK * 4;
    float*  bs      = (float*) (ws + off); off += (size_t)NB * 32 * 4;
    float2* cs      = (float2*)(ws + off); off += (size_t)NB * 32 * 8;
    float*  Gval    = (float*) (ws + off); off += (size_t)NB * 32 * 4;
    float*  Hval    = (float*) (ws + off); off += (size_t)NB * 32 * 4;
    float*  partial = (float*) (ws + off); off += (size_t)NB * 4;

    prep_kernel<<<NB, 64, 0, stream>>>(features, fh, sq);
    gram_kernel<<<(NB / BM) * (NB / BM), 256, 0, stream>>>(fh, sq, dist);
    topk6_kernel<<<NB / 4, 256, 0, stream>>>(dist, idxk, dk, sigma);
    buildp_kernel<<<NB, 64, 0, stream>>>(idxk, dk, sigma, labels, scores, pval, bs, cs);
    hval_kernel<<<NB / 4, 256, 0, stream>>>(idxk, pval, scores, bs, cs, Gval, Hval);
    loss_kernel<<<NB / 4, 256, 0, stream>>>(scores, idxk, pval, Gval, Hval, partial);
    reduce_kernel<<<1, 256, 0, stream>>>(partial, out);
}